// Round 1
// baseline (197.548 us; speedup 1.0000x reference)
//
#include <hip/hip_runtime.h>

#define NSAMP 131072
#define DIMS 8
#define NPCE 495
#define KP 512          // K padded to 512
#define NOUT 256
#define BM 64           // samples per block
#define SK 64           // K per pipeline stage
#define NSTG (KP / SK)  // 8 stages
#define NH 70           // half-products per 4-dim half (order<=4)
#define HS 68           // At/Bt sample stride: 136B, words==2 mod 32 -> banks spread by h
#define PS 72           // Psi row stride: 144B, words==4 mod 32 -> min-conflict writes+reads

typedef _Float16 half8 __attribute__((ext_vector_type(8)));
typedef _Float16 h16x2 __attribute__((ext_vector_type(2)));
typedef float f32x4 __attribute__((ext_vector_type(4)));
typedef unsigned short u16x4 __attribute__((ext_vector_type(4)));

__device__ __forceinline__ unsigned short f2h(float f) {
    return __builtin_bit_cast(unsigned short, (_Float16)f);  // v_cvt_f16_f32, RTNE
}

// packed f16 multiply of two sample-pairs: one v_pk_mul_f16
__device__ __forceinline__ unsigned pkmul(unsigned a, unsigned b) {
    h16x2 r = __builtin_bit_cast(h16x2, a) * __builtin_bit_cast(h16x2, b);
    return __builtin_bit_cast(unsigned, r);
}

// Rank of 4-dim multi-index (sum<=4) in the canonical nest enumeration.
__device__ int rank4(int a0, int a1, int a2, int a3) {
    int idx = 0;
    for (int b0 = 0; b0 <= 4; ++b0)
        for (int b1 = 0; b1 <= 4 - b0; ++b1)
            for (int b2 = 0; b2 <= 4 - b0 - b1; ++b2)
                for (int b3 = 0; b3 <= 4 - b0 - b1 - b2; ++b3) {
                    if (b0 == a0 && b1 == a1 && b2 == a2 && b3 == a3) return idx;
                    ++idx;
                }
    return 0;
}

// prep: weight -> f16 [256][512] with PERMUTED rows (epilogue dwordx4 stores):
// row n holds original column o = (n&~63) | ((n&15)<<2) | ((n>>4)&3).
// mi[k][8] -> u16 code h1 | (h2<<8).
__global__ __launch_bounds__(256) void prep_kernel(const float* __restrict__ w,
                                                   const int* __restrict__ mi,
                                                   unsigned short* __restrict__ wb,
                                                   unsigned short* __restrict__ hcode) {
    int t = blockIdx.x * 256 + threadIdx.x;
    if (t < NOUT * KP) {
        int n = t >> 9;
        int k = t & (KP - 1);
        int o = (n & ~63) | ((n & 15) << 2) | ((n >> 4) & 3);
        float v = (k < NPCE) ? w[o * NPCE + k] : 0.0f;
        wb[t] = f2h(v);
    }
    if (t < KP) {
        int code = 0;
        if (t < NPCE) {
            const int* m = &mi[t * DIMS];
            int h1 = rank4(m[0], m[1], m[2], m[3]);
            int h2 = rank4(m[4], m[5], m[6], m[7]);
            code = h1 | (h2 << 8);
        }
        hcode[t] = (unsigned short)code;
    }
}

// Build 35 of the 70 half-products (compile-time range -> full DCE/CSE).
template <int LO, int HI>
__device__ __forceinline__ void build_half(const float H0[5], const float H1[5],
                                           const float H2[5], const float H3[5],
                                           unsigned short* dst, int s) {
    int idx = 0;
    #pragma unroll
    for (int a0 = 0; a0 <= 4; ++a0)
        #pragma unroll
        for (int a1 = 0; a1 <= 4 - a0; ++a1)
            #pragma unroll
            for (int a2 = 0; a2 <= 4 - a0 - a1; ++a2)
                #pragma unroll
                for (int a3 = 0; a3 <= 4 - a0 - a1 - a2; ++a3) {
                    if (idx >= LO && idx < HI) {
                        float p = H0[a0] * H1[a1] * H2[a2] * H3[a3];
                        dst[idx * HS + s] = f2h(p);
                    }
                    ++idx;
                }
}

__device__ __forceinline__ void hermite5(float x, float H[5]) {
    const float rn2 = 0.70710678118654752f;
    const float rn3 = 0.40824829046386302f;
    const float rn4 = 0.20412414523193151f;
    float r1 = x;
    float r2 = x * r1 - 1.0f;
    float r3 = x * r2 - 2.0f * r1;
    float r4 = x * r3 - 3.0f * r2;
    H[0] = 1.0f; H[1] = r1; H[2] = r2 * rn2; H[3] = r3 * rn3; H[4] = r4 * rn4;
}

__global__ __launch_bounds__(256, 3) void pce_kernel(const float* __restrict__ x,
                                                     const unsigned short* __restrict__ wb,
                                                     const unsigned short* __restrict__ hcode,
                                                     float* __restrict__ out) {
    __shared__ __attribute__((aligned(16))) unsigned short At[NH * HS];     // 9.52 KB
    __shared__ __attribute__((aligned(16))) unsigned short Bt[NH * HS];     // 9.52 KB
    __shared__ __attribute__((aligned(16))) unsigned short Psi[2][BM * PS]; // 18.4 KB
    __shared__ __attribute__((aligned(16))) unsigned short hc[KP];          // 1 KB

    const int tid = threadIdx.x;
    const int lane = tid & 63;
    const int wave = tid >> 6;
    const int quad = lane >> 4;
    const int l15 = lane & 15;
    const int m0 = blockIdx.x * BM;

    // Gather mapping: thread owns 4 k (group u16k) x 4 samples (s0..s0+3).
    const int u16k = tid & 15;
    const int s0 = (tid >> 4) * 4;

    // ---- Builder: wave -> (half = wave>>1, term range = wave&1), lane = sample.
    {
        const int half = wave >> 1;
        const float4 xv = *(const float4*)&x[(m0 + lane) * DIMS + half * 4];
        float H0[5], H1[5], H2[5], H3[5];
        hermite5(xv.x, H0);
        hermite5(xv.y, H1);
        hermite5(xv.z, H2);
        hermite5(xv.w, H3);
        unsigned short* dst = half ? Bt : At;
        if (wave & 1) build_half<35, 70>(H0, H1, H2, H3, dst, lane);
        else          build_half<0, 35>(H0, H1, H2, H3, dst, lane);
    }
    // hcode -> LDS once (removes a global load from every stage's gather chain)
    if (tid < KP / 4) ((uint2*)hc)[tid] = ((const uint2*)hcode)[tid];

    f32x4 acc[4][4] = {};

    // Gather one 64-wide stage into Psi[buf]:
    // 1 ds_read_b64 (codes) + 8 ds_read_b64 (At/Bt) + 8 v_pk_mul_f16 + 8 v_perm_b32
    // + 4 ds_write_b64. No float<->f16 conversion code at all.
    auto gather = [&](int stage, int buf) {
        u16x4 cds = *(const u16x4*)&hc[stage * SK + u16k * 4];
        unsigned plo[4], phi[4];   // per k: packed products (s0,s1) and (s2,s3)
        #pragma unroll
        for (int j = 0; j < 4; ++j) {
            int h1 = cds[j] & 255;
            int h2 = cds[j] >> 8;
            uint2 av = *(const uint2*)&At[h1 * HS + s0];
            uint2 bv = *(const uint2*)&Bt[h2 * HS + s0];
            plo[j] = pkmul(av.x, bv.x);
            phi[j] = pkmul(av.y, bv.y);
        }
        // transpose sample-pairs -> k-major rows via v_perm_b32 (1 op / 2 values)
        uint2 w;
        w.x = __builtin_amdgcn_perm(plo[1], plo[0], 0x05040100u);
        w.y = __builtin_amdgcn_perm(plo[3], plo[2], 0x05040100u);
        *(uint2*)&Psi[buf][(s0 + 0) * PS + u16k * 4] = w;
        w.x = __builtin_amdgcn_perm(plo[1], plo[0], 0x07060302u);
        w.y = __builtin_amdgcn_perm(plo[3], plo[2], 0x07060302u);
        *(uint2*)&Psi[buf][(s0 + 1) * PS + u16k * 4] = w;
        w.x = __builtin_amdgcn_perm(phi[1], phi[0], 0x05040100u);
        w.y = __builtin_amdgcn_perm(phi[3], phi[2], 0x05040100u);
        *(uint2*)&Psi[buf][(s0 + 2) * PS + u16k * 4] = w;
        w.x = __builtin_amdgcn_perm(phi[1], phi[0], 0x07060302u);
        w.y = __builtin_amdgcn_perm(phi[3], phi[2], 0x07060302u);
        *(uint2*)&Psi[buf][(s0 + 3) * PS + u16k * 4] = w;
    };

    __syncthreads();   // At/Bt + hc ready
    gather(0, 0);

    #pragma unroll 2
    for (int s = 0; s < NSTG; ++s) {
        __syncthreads();  // Psi[s&1] writes visible; Psi[(s+1)&1] reads drained
        if (s < NSTG - 1) gather(s + 1, (s + 1) & 1);  // overlaps with MFMA below
        #pragma unroll
        for (int ks = 0; ks < SK / 32; ++ks) {
            half8 af[4], bfr[4];
            #pragma unroll
            for (int im = 0; im < 4; ++im) {
                int row = im * 16 + l15;
                af[im] = *(const half8*)&Psi[s & 1][row * PS + ks * 32 + quad * 8];
            }
            #pragma unroll
            for (int in = 0; in < 4; ++in) {
                int n = wave * 64 + in * 16 + l15;
                bfr[in] = *(const half8*)&wb[n * KP + s * SK + ks * 32 + quad * 8];
            }
            #pragma unroll
            for (int im = 0; im < 4; ++im)
                #pragma unroll
                for (int in = 0; in < 4; ++in)
                    acc[im][in] = __builtin_amdgcn_mfma_f32_16x16x32_f16(
                        af[im], bfr[in], acc[im][in], 0, 0, 0);
        }
    }

    // ---- epilogue: permuted weights make lane's 4 'in' values 4 consecutive
    // output columns -> coalesced dwordx4 stores (16 per thread).
    #pragma unroll
    for (int im = 0; im < 4; ++im) {
        #pragma unroll
        for (int i = 0; i < 4; ++i) {
            int m = m0 + im * 16 + quad * 4 + i;
            float4 v = make_float4(acc[im][0][i], acc[im][1][i],
                                   acc[im][2][i], acc[im][3][i]);
            *(float4*)&out[m * NOUT + wave * 64 + l15 * 4] = v;
        }
    }
}

extern "C" void kernel_launch(void* const* d_in, const int* in_sizes, int n_in,
                              void* d_out, int out_size, void* d_ws, size_t ws_size,
                              hipStream_t stream) {
    const float* x = (const float*)d_in[0];
    const float* w = (const float*)d_in[1];
    const int* mi = (const int*)d_in[2];
    float* out = (float*)d_out;

    unsigned short* wb = (unsigned short*)d_ws;                              // 256 KB
    unsigned short* hcode = (unsigned short*)((char*)d_ws + NOUT * KP * 2);  // 1 KB

    prep_kernel<<<(NOUT * KP + 255) / 256, 256, 0, stream>>>(w, mi, wb, hcode);
    pce_kernel<<<NSAMP / BM, 256, 0, stream>>>(x, wb, hcode, out);
}